// Round 4
// baseline (1196.307 us; speedup 1.0000x reference)
//
#include <hip/hip_runtime.h>
#include <hip/hip_bf16.h>
#include <cstdint>

#define T_LEN 4096
#define NBATCH 8
#define DD 2048
#define KK 64
#define VV 128
#define CH 64
#define NC (T_LEN / CH)
#define NPROJ 384

// ------------------------------------------------------------------
// Build Wcat [2048][384] = [Wq | Wk | Wb | Wd | Wv]
// ------------------------------------------------------------------
__global__ void k_concat(const float* __restrict__ Wq, const float* __restrict__ Wk,
                         const float* __restrict__ Wb, const float* __restrict__ Wd,
                         const float* __restrict__ Wv, float* __restrict__ Wcat) {
  int idx = blockIdx.x * 256 + threadIdx.x;
  if (idx >= DD * NPROJ) return;
  int d = idx / NPROJ, j = idx % NPROJ;
  float val;
  if (j < 64)       val = Wq[d * 64 + j];
  else if (j < 128) val = Wk[d * 64 + (j - 64)];
  else if (j < 192) val = Wb[d * 64 + (j - 128)];
  else if (j < 256) val = Wd[d * 64 + (j - 192)];
  else              val = Wv[d * 128 + (j - 256)];
  Wcat[idx] = val;
}

// ------------------------------------------------------------------
// fp32 tiled GEMM: C[M,N] = A[M,Kd] * B[Kd,N], all row-major.
// BM=128, BN=128, BK=32, 256 threads, 8x8 micro-tile.
// Requires M%128==0, N%128==0, Kd%32==0.
// ------------------------------------------------------------------
#define BM 128
#define BN 128
#define BKT 32

__global__ __launch_bounds__(256) void k_gemm(const float* __restrict__ A,
                                              const float* __restrict__ B,
                                              float* __restrict__ C,
                                              int Kd, int lda, int ldb, int ldc) {
  __shared__ float As[BKT][BM + 4];   // transposed: As[k][m], row pad 132 (16B aligned)
  __shared__ float Bs[BKT][BN];
  int bm = blockIdx.x, bn = blockIdx.y;
  int tid = threadIdx.x;
  int ty = tid >> 4, tx = tid & 15;
  const float* Ab = A + (size_t)bm * BM * lda;
  const float* Bb = B + (size_t)bn * BN;
  float acc[8][8];
#pragma unroll
  for (int i = 0; i < 8; ++i)
#pragma unroll
    for (int j = 0; j < 8; ++j) acc[i][j] = 0.f;

  for (int kt = 0; kt < Kd; kt += BKT) {
#pragma unroll
    for (int p = 0; p < 4; ++p) {
      int lin = tid + p * 256;
      int row = lin >> 3, c4 = (lin & 7) * 4;
      float4 a = *(const float4*)(Ab + (size_t)row * lda + kt + c4);
      As[c4 + 0][row] = a.x; As[c4 + 1][row] = a.y;
      As[c4 + 2][row] = a.z; As[c4 + 3][row] = a.w;
    }
#pragma unroll
    for (int p = 0; p < 4; ++p) {
      int lin = tid + p * 256;
      int row = lin >> 5, c4 = (lin & 31) * 4;
      *(float4*)&Bs[row][c4] = *(const float4*)(Bb + (size_t)(kt + row) * ldb + c4);
    }
    __syncthreads();
#pragma unroll
    for (int kk = 0; kk < BKT; ++kk) {
      float4 a0 = *(const float4*)&As[kk][ty * 8];
      float4 a1 = *(const float4*)&As[kk][ty * 8 + 4];
      float4 b0 = *(const float4*)&Bs[kk][tx * 8];
      float4 b1 = *(const float4*)&Bs[kk][tx * 8 + 4];
      float av[8] = {a0.x, a0.y, a0.z, a0.w, a1.x, a1.y, a1.z, a1.w};
      float bv[8] = {b0.x, b0.y, b0.z, b0.w, b1.x, b1.y, b1.z, b1.w};
#pragma unroll
      for (int i = 0; i < 8; ++i)
#pragma unroll
        for (int j = 0; j < 8; ++j)
          acc[i][j] = fmaf(av[i], bv[j], acc[i][j]);
    }
    __syncthreads();
  }
  float* Cp = C + (size_t)(bm * BM + ty * 8) * ldc + bn * BN + tx * 8;
#pragma unroll
  for (int i = 0; i < 8; ++i) {
    *(float4*)(Cp + (size_t)i * ldc)     = make_float4(acc[i][0], acc[i][1], acc[i][2], acc[i][3]);
    *(float4*)(Cp + (size_t)i * ldc + 4) = make_float4(acc[i][4], acc[i][5], acc[i][6], acc[i][7]);
  }
}

// ------------------------------------------------------------------
// Per-chunk gate preprocessing.
// proj row layout: [q(64) | k(64) | braw(64) | draw(64) | v(128)]
// Writes qg, kg (decay-folded), qS = q*exp(G), Rall[14][64], Dc[64].
// Sub-block bases keep all stored exponents <= 0; R factors bounded by e^{+56}.
// ------------------------------------------------------------------
__global__ __launch_bounds__(256) void k_pre(const float* __restrict__ proj,
                                             const float* __restrict__ bb,
                                             const float* __restrict__ bd,
                                             float* __restrict__ qg,
                                             float* __restrict__ kgl,
                                             float* __restrict__ qS,
                                             float* __restrict__ Rall,
                                             float* __restrict__ Dc) {
  __shared__ float G[CH][KK];
  __shared__ float Eb[5][KK];
  int bc = blockIdx.x;
  size_t bt0 = (size_t)bc * CH;
  int tid = threadIdx.x;

  // 1. log beta = -log1p(exp(-(braw+bb)))
#pragma unroll
  for (int p = 0; p < 4; ++p) {
    int lin = tid + p * 256;
    int row = lin >> 4, c4 = (lin & 15) * 4;
    float4 z = *(const float4*)(proj + (bt0 + row) * NPROJ + 128 + c4);
    float4 b4 = *(const float4*)(bb + c4);
    G[row][c4 + 0] = -log1pf(expf(-(z.x + b4.x)));
    G[row][c4 + 1] = -log1pf(expf(-(z.y + b4.y)));
    G[row][c4 + 2] = -log1pf(expf(-(z.z + b4.z)));
    G[row][c4 + 3] = -log1pf(expf(-(z.w + b4.w)));
  }
  __syncthreads();

  // 2. inclusive cumsum per k; record block-boundary values
  if (tid < KK) {
    float run = 0.f;
    Eb[0][tid] = 0.f;
    for (int t = 0; t < CH; ++t) {
      run += G[t][tid];
      G[t][tid] = run;
      if ((t & 15) == 15) Eb[(t >> 4) + 1][tid] = run;
    }
  }
  __syncthreads();

  // 3. R factors: 10 (I,J) pairs (J<=I) + 4 RM rows; Dc
  for (int p = tid; p < 14 * KK; p += 256) {
    int pr = p >> 6, k = p & 63;
    float e;
    if (pr < 10) {
      int I = (pr >= 6) ? 3 : (pr >= 3) ? 2 : (pr >= 1) ? 1 : 0;
      int J = pr - I * (I + 1) / 2;
      e = Eb[I][k] - Eb[J + 1][k];
    } else {
      e = Eb[4][k] - Eb[pr - 10 + 1][k];
    }
    Rall[(size_t)bc * 14 * KK + p] = expf(e);
  }
  if (tid < KK) Dc[(size_t)bc * KK + tid] = expf(Eb[4][tid]);

  // 4. q -> qS (chunk-start base) and qg (sub-block-start base)
#pragma unroll
  for (int p = 0; p < 4; ++p) {
    int lin = tid + p * 256;
    int row = lin >> 4, c4 = (lin & 15) * 4;
    int I = row >> 4;
    float4 q4 = *(const float4*)(proj + (bt0 + row) * NPROJ + 0 + c4);
    float qv[4] = {q4.x, q4.y, q4.z, q4.w};
    float qs[4], qq[4];
#pragma unroll
    for (int e = 0; e < 4; ++e) {
      int k = c4 + e;
      float Gv = G[row][k];
      qs[e] = qv[e] * expf(Gv);
      qq[e] = qv[e] * expf(Gv - Eb[I][k]);
    }
    *(float4*)(qS + (bt0 + row) * KK + c4) = make_float4(qs[0], qs[1], qs[2], qs[3]);
    *(float4*)(qg + (bt0 + row) * KK + c4) = make_float4(qq[0], qq[1], qq[2], qq[3]);
  }

  // 5. k,delta -> kg (sub-block-end base; exponent <= 0)
#pragma unroll
  for (int p = 0; p < 4; ++p) {
    int lin = tid + p * 256;
    int row = lin >> 4, c4 = (lin & 15) * 4;
    int J1 = (row >> 4) + 1;
    float4 k4 = *(const float4*)(proj + (bt0 + row) * NPROJ + 64 + c4);
    float4 d4 = *(const float4*)(proj + (bt0 + row) * NPROJ + 192 + c4);
    float4 bd4 = *(const float4*)(bd + c4);
    float kv[4] = {k4.x, k4.y, k4.z, k4.w};
    float dv[4] = {d4.x, d4.y, d4.z, d4.w};
    float bdv[4] = {bd4.x, bd4.y, bd4.z, bd4.w};
    float ko[4];
#pragma unroll
    for (int e = 0; e < 4; ++e) {
      int k = c4 + e;
      float z = dv[e] + bdv[e];
      float delta = (z > 15.f) ? z : log1pf(expf(z));
      ko[e] = kv[e] * delta * expf(Eb[J1][k] - G[row][k]);
    }
    *(float4*)(kgl + (bt0 + row) * KK + c4) = make_float4(ko[0], ko[1], ko[2], ko[3]);
  }
}

// ------------------------------------------------------------------
// Per-chunk main: scores A (causal), o_intra = A*v, M_c = (kg.*RM)^T * v
// ------------------------------------------------------------------
__global__ __launch_bounds__(256) void k_main(const float* __restrict__ proj,
                                              const float* __restrict__ qg,
                                              const float* __restrict__ kgl,
                                              const float* __restrict__ Rall,
                                              float* __restrict__ obuf,
                                              float* __restrict__ Mc) {
  __shared__ float bufA[CH][KK + 1];   // qg^T [k][i], then Asc^T [j][i]
  __shared__ float bufB[CH][KK + 1];   // kg^T [k][j]
  __shared__ float bufV[CH][VV];       // v [j][vc]
  int bc = blockIdx.x;
  size_t bt0 = (size_t)bc * CH;
  int tid = threadIdx.x;

#pragma unroll
  for (int p = 0; p < 4; ++p) {
    int lin = tid + p * 256;
    int row = lin >> 4, c4 = (lin & 15) * 4;
    float4 a = *(const float4*)(qg + (bt0 + row) * KK + c4);
    bufA[c4 + 0][row] = a.x; bufA[c4 + 1][row] = a.y;
    bufA[c4 + 2][row] = a.z; bufA[c4 + 3][row] = a.w;
    float4 b = *(const float4*)(kgl + (bt0 + row) * KK + c4);
    bufB[c4 + 0][row] = b.x; bufB[c4 + 1][row] = b.y;
    bufB[c4 + 2][row] = b.z; bufB[c4 + 3][row] = b.w;
  }
#pragma unroll
  for (int p = 0; p < 8; ++p) {
    int lin = tid + p * 256;
    int row = lin >> 5, c4 = (lin & 31) * 4;
    *(float4*)&bufV[row][c4] = *(const float4*)(proj + (bt0 + row) * NPROJ + 256 + c4);
  }
  __syncthreads();

  // scores: thread -> 4x4 tile at (im*4, jm*4)
  int im = tid >> 4, jm = tid & 15;
  int I = im >> 2, J = jm >> 2;
  float sacc[4][4];
#pragma unroll
  for (int d = 0; d < 4; ++d)
#pragma unroll
    for (int e = 0; e < 4; ++e) sacc[d][e] = 0.f;
  if (J <= I) {
    const float* Rp = Rall + ((size_t)bc * 14 + (I * (I + 1) / 2 + J)) * KK;
    for (int k = 0; k < KK; ++k) {
      float r = Rp[k];
      float qa[4], kb[4];
#pragma unroll
      for (int d = 0; d < 4; ++d) qa[d] = bufA[k][im * 4 + d] * r;
#pragma unroll
      for (int e = 0; e < 4; ++e) kb[e] = bufB[k][jm * 4 + e];
#pragma unroll
      for (int d = 0; d < 4; ++d)
#pragma unroll
        for (int e = 0; e < 4; ++e) sacc[d][e] = fmaf(qa[d], kb[e], sacc[d][e]);
    }
  }
  __syncthreads();
#pragma unroll
  for (int d = 0; d < 4; ++d)
#pragma unroll
    for (int e = 0; e < 4; ++e) {
      int i = im * 4 + d, j = jm * 4 + e;
      bufA[j][i] = (j <= i) ? sacc[d][e] : 0.f;
    }
  __syncthreads();

  int g8 = tid >> 5;   // 0..7 (8 rows each)
  int vm = tid & 31;   // 0..31 (4 v-cols each)

  // o_intra = Asc * v (triangular: j <= max row of this group)
  {
    float accO[8][4];
#pragma unroll
    for (int d = 0; d < 8; ++d)
#pragma unroll
      for (int e = 0; e < 4; ++e) accO[d][e] = 0.f;
    int jmax = g8 * 8 + 8;
    for (int j = 0; j < jmax; ++j) {
      float4 v4 = *(const float4*)&bufV[j][vm * 4];
      float vv[4] = {v4.x, v4.y, v4.z, v4.w};
#pragma unroll
      for (int d = 0; d < 8; ++d) {
        float a = bufA[j][g8 * 8 + d];
#pragma unroll
        for (int e = 0; e < 4; ++e) accO[d][e] = fmaf(a, vv[e], accO[d][e]);
      }
    }
#pragma unroll
    for (int d = 0; d < 8; ++d)
      *(float4*)(obuf + (bt0 + g8 * 8 + d) * VV + vm * 4) =
          make_float4(accO[d][0], accO[d][1], accO[d][2], accO[d][3]);
  }

  // M_c[k][v] = sum_j kg[j][k] * RM[J(j)][k] * v[j][v]
  {
    float accM[8][4];
#pragma unroll
    for (int d = 0; d < 8; ++d)
#pragma unroll
      for (int e = 0; e < 4; ++e) accM[d][e] = 0.f;
    for (int J2 = 0; J2 < 4; ++J2) {
      float rm[8];
#pragma unroll
      for (int d = 0; d < 8; ++d)
        rm[d] = Rall[((size_t)bc * 14 + 10 + J2) * KK + g8 * 8 + d];
      for (int j = J2 * 16; j < J2 * 16 + 16; ++j) {
        float4 v4 = *(const float4*)&bufV[j][vm * 4];
        float vv[4] = {v4.x, v4.y, v4.z, v4.w};
#pragma unroll
        for (int d = 0; d < 8; ++d) {
          float kv = bufB[g8 * 8 + d][j] * rm[d];
#pragma unroll
          for (int e = 0; e < 4; ++e) accM[d][e] = fmaf(kv, vv[e], accM[d][e]);
        }
      }
    }
#pragma unroll
    for (int d = 0; d < 8; ++d)
      *(float4*)(Mc + ((size_t)bc * KK + g8 * 8 + d) * VV + vm * 4) =
          make_float4(accM[d][0], accM[d][1], accM[d][2], accM[d][3]);
  }
}

// ------------------------------------------------------------------
// Inter-chunk scan: one wave per (b,k) row; stores chunk-START states.
// Needs NBATCH*KK = 512 waves -> 128 blocks of 256.
// ------------------------------------------------------------------
__global__ __launch_bounds__(256) void k_scan(const float* __restrict__ Mc,
                                              const float* __restrict__ Dc,
                                              float* __restrict__ S0) {
  int gtid = blockIdx.x * 256 + threadIdx.x;
  int wid = gtid >> 6;        // 0..511
  int lane = gtid & 63;
  int b = wid >> 6, k = wid & 63;
  float sx = 0.f, sy = 0.f;
  for (int c = 0; c < NC; ++c) {
    size_t off = ((size_t)(b * NC + c) * KK + k) * VV + lane * 2;
    *(float2*)(S0 + off) = make_float2(sx, sy);
    float2 m = *(const float2*)(Mc + off);
    float d = Dc[(size_t)(b * NC + c) * KK + k];
    sx = fmaf(d, sx, m.x);
    sy = fmaf(d, sy, m.y);
  }
}

// ------------------------------------------------------------------
// o += qS * S0(chunk)
// ------------------------------------------------------------------
__global__ __launch_bounds__(256) void k_inter(const float* __restrict__ qS,
                                               const float* __restrict__ S0,
                                               float* __restrict__ obuf) {
  __shared__ float qT[KK][CH + 1];
  __shared__ float Sb[KK][VV];
  int bc = blockIdx.x;
  size_t bt0 = (size_t)bc * CH;
  int tid = threadIdx.x;
#pragma unroll
  for (int p = 0; p < 4; ++p) {
    int lin = tid + p * 256;
    int row = lin >> 4, c4 = (lin & 15) * 4;
    float4 a = *(const float4*)(qS + (bt0 + row) * KK + c4);
    qT[c4 + 0][row] = a.x; qT[c4 + 1][row] = a.y;
    qT[c4 + 2][row] = a.z; qT[c4 + 3][row] = a.w;
  }
#pragma unroll
  for (int p = 0; p < 8; ++p) {
    int lin = tid + p * 256;
    int row = lin >> 5, c4 = (lin & 31) * 4;
    *(float4*)&Sb[row][c4] = *(const float4*)(S0 + ((size_t)bc * KK + row) * VV + c4);
  }
  __syncthreads();
  int g8 = tid >> 5, vm = tid & 31;
  float acc[8][4];
#pragma unroll
  for (int d = 0; d < 8; ++d)
#pragma unroll
    for (int e = 0; e < 4; ++e) acc[d][e] = 0.f;
  for (int k = 0; k < KK; ++k) {
    float4 v4 = *(const float4*)&Sb[k][vm * 4];
    float vv[4] = {v4.x, v4.y, v4.z, v4.w};
#pragma unroll
    for (int d = 0; d < 8; ++d) {
      float a = qT[k][g8 * 8 + d];
#pragma unroll
      for (int e = 0; e < 4; ++e) acc[d][e] = fmaf(a, vv[e], acc[d][e]);
    }
  }
#pragma unroll
  for (int d = 0; d < 8; ++d) {
    float* op = obuf + (bt0 + g8 * 8 + d) * VV + vm * 4;
    float4 cur = *(float4*)op;
    cur.x += acc[d][0]; cur.y += acc[d][1]; cur.z += acc[d][2]; cur.w += acc[d][3];
    *(float4*)op = cur;
  }
}

// ------------------------------------------------------------------
extern "C" void kernel_launch(void* const* d_in, const int* in_sizes, int n_in,
                              void* d_out, int out_size, void* d_ws, size_t ws_size,
                              hipStream_t stream) {
  const float* x  = (const float*)d_in[0];
  const float* Wq = (const float*)d_in[1];
  const float* Wk = (const float*)d_in[2];
  const float* Wv = (const float*)d_in[3];
  const float* Wo = (const float*)d_in[4];
  const float* Wb = (const float*)d_in[5];
  const float* bb = (const float*)d_in[6];
  const float* Wd = (const float*)d_in[7];
  const float* bd = (const float*)d_in[8];
  float* out = (float*)d_out;
  float* ws = (float*)d_ws;

  float* Wcat = ws;                         // 786,432
  float* proj = Wcat + 786432;              // 12,582,912
  float* qg   = proj + 12582912;            // 2,097,152
  float* kgl  = qg   + 2097152;             // 2,097,152
  float* qSb  = kgl  + 2097152;             // 2,097,152
  float* Rall = qSb  + 2097152;             // 458,752
  float* Dc   = Rall + 458752;              // 32,768
  float* Mc   = Dc   + 32768;               // 4,194,304
  float* S0   = Mc   + 4194304;             // 4,194,304
  float* obuf = S0   + 4194304;             // 4,194,304  (total ~125 MB)

  k_concat<<<dim3((DD * NPROJ + 255) / 256), dim3(256), 0, stream>>>(Wq, Wk, Wb, Wd, Wv, Wcat);
  // proj = x @ Wcat : M=32768, N=384, K=2048
  k_gemm<<<dim3(256, 3), dim3(256), 0, stream>>>(x, Wcat, proj, DD, DD, NPROJ, NPROJ);
  k_pre<<<dim3(NBATCH * NC), dim3(256), 0, stream>>>(proj, bb, bd, qg, kgl, qSb, Rall, Dc);
  k_main<<<dim3(NBATCH * NC), dim3(256), 0, stream>>>(proj, qg, kgl, Rall, obuf, Mc);
  k_scan<<<dim3(128), dim3(256), 0, stream>>>(Mc, Dc, S0);  // 512 waves = one per (b,k)
  k_inter<<<dim3(NBATCH * NC), dim3(256), 0, stream>>>(qSb, S0, obuf);
  // out = obuf @ Wo : M=32768, N=2048, K=128
  k_gemm<<<dim3(256, 16), dim3(256), 0, stream>>>(obuf, Wo, out, VV, VV, DD, DD);
}